// Round 1
// baseline (226.022 us; speedup 1.0000x reference)
//
#include <hip/hip_runtime.h>

#define N_USERS 100000
#define N_ITEMS 50000
#define N_NODES 150000   // N_USERS + N_ITEMS
#define NNZ     1200000
#define DIM     64
#define BATCH   16384

// ---------------------------------------------------------------------------
// K1: mark which prop rows are actually read by the score step.
// flags[node] = 1 iff node appears in u (users) or N_USERS + i (items).
// Idempotent byte stores -> no atomics needed.
// ---------------------------------------------------------------------------
__global__ void mark_flags_kernel(const int* __restrict__ u,
                                  const int* __restrict__ it,
                                  unsigned char* __restrict__ flags) {
    int t = blockIdx.x * blockDim.x + threadIdx.x;
    if (t < BATCH) {
        flags[u[t]] = 1;
    } else if (t < 2 * BATCH) {
        flags[N_USERS + it[t - BATCH]] = 1;
    }
}

// ---------------------------------------------------------------------------
// K2: filtered scatter. One wave64 per edge (lane = dim), grid-stride.
// Reads per edge: row/col/val (broadcast), flags[row] (hot 150KB table).
// Surviving edges (~20%): coalesced 256B gather of the source embedding,
// coalesced 256B atomic accumulate into prop[row].
// ---------------------------------------------------------------------------
__global__ void scatter_edges_kernel(const float* __restrict__ user_emb,
                                     const float* __restrict__ item_emb,
                                     const int*   __restrict__ rows,
                                     const int*   __restrict__ cols,
                                     const float* __restrict__ vals,
                                     const unsigned char* __restrict__ flags,
                                     float* __restrict__ prop) {
    const int lane  = threadIdx.x & 63;
    const int wib   = threadIdx.x >> 6;              // wave index in block
    const int wpb   = blockDim.x >> 6;               // waves per block
    long long wave  = (long long)blockIdx.x * wpb + wib;
    long long nwav  = (long long)gridDim.x * wpb;

    for (long long e = wave; e < NNZ; e += nwav) {
        int r = rows[e];                              // wave-uniform
        if (!flags[r]) continue;                      // uniform branch, no divergence
        int   c = cols[e];
        float v = vals[e];
        const float* emb = (c < N_USERS)
                             ? (user_emb + (long long)c * DIM)
                             : (item_emb + (long long)(c - N_USERS) * DIM);
        float m = v * emb[lane];
        unsafeAtomicAdd(&prop[(long long)r * DIM + lane], m);
    }
}

// ---------------------------------------------------------------------------
// K3: scores. One wave64 per (u,i) pair; lane = dim; shfl reduction.
// ---------------------------------------------------------------------------
__global__ void score_kernel(const float* __restrict__ prop,
                             const int* __restrict__ u,
                             const int* __restrict__ it,
                             float* __restrict__ out) {
    const int lane = threadIdx.x & 63;
    const int wave = (int)(((long long)blockIdx.x * blockDim.x + threadIdx.x) >> 6);
    if (wave >= BATCH) return;

    const float* up = prop + (long long)u[wave] * DIM;
    const float* ip = prop + (long long)(N_USERS + it[wave]) * DIM;
    float p = up[lane] * ip[lane];

    // 64-lane tree reduction
    #pragma unroll
    for (int off = 32; off > 0; off >>= 1)
        p += __shfl_down(p, off, 64);

    if (lane == 0) out[wave] = p;
}

extern "C" void kernel_launch(void* const* d_in, const int* in_sizes, int n_in,
                              void* d_out, int out_size, void* d_ws, size_t ws_size,
                              hipStream_t stream) {
    const float* user_emb = (const float*)d_in[0];
    const float* item_emb = (const float*)d_in[1];
    const int*   rows     = (const int*)d_in[2];
    const int*   cols     = (const int*)d_in[3];
    const float* vals     = (const float*)d_in[4];
    const int*   u        = (const int*)d_in[5];
    const int*   it       = (const int*)d_in[6];
    float*       out      = (float*)d_out;

    // ws layout: [prop: 150000*64 f32 = 38.4MB][flags: 150000 bytes]
    float*         prop  = (float*)d_ws;
    unsigned char* flags = (unsigned char*)d_ws + (size_t)N_NODES * DIM * sizeof(float);

    const size_t zero_bytes = (size_t)N_NODES * DIM * sizeof(float) + N_NODES;
    hipMemsetAsync(d_ws, 0, zero_bytes, stream);

    mark_flags_kernel<<<(2 * BATCH + 255) / 256, 256, 0, stream>>>(u, it, flags);

    // 2048 blocks * 4 waves = 8192 waves; ~147 edges per wave grid-stride.
    scatter_edges_kernel<<<2048, 256, 0, stream>>>(user_emb, item_emb, rows, cols,
                                                   vals, flags, prop);

    score_kernel<<<(BATCH * 64 + 255) / 256, 256, 0, stream>>>(prop, u, it, out);
}